// Round 9
// baseline (3566.432 us; speedup 1.0000x reference)
//
#include <hip/hip_runtime.h>
#include <hip/hip_fp16.h>

// RNN h_{t+1} = tanh(x_t*W_ih + b_ih + b_hh + h_t @ W_hh^T), T=1024, B=64, H=512.
//
// Round 9: barrier-free wave-autonomous slices. 256 WGs (4/batch) x 256 thr.
// Each WAVE independently owns 32 rows x full k=512 and is its own publisher:
//  - weights: 128 uints fp16/thread in arch VGPRs (R2-proven size at 256 thr;
//    512-thr WGs are empirically capped at 128 arch VGPRs -> AGPR tax, R3-R8).
//  - k halved across lane halves (c=lane>>5); combine = ONE shfl_xor(32).
//    No parts LDS, no __syncthreads in the loop, no intra-WG coupling.
//  - exchange: 4B word {tag:16 | fp16 h:16} per row, parity double-buffered.
//    publish = __hip_atomic_store AGENT RELAXED (R2-proven, ~400cy visible).
//    poll = 8 x __hip_atomic_load dword AGENT RELAXED per lane (rows 8l..8l+7),
//    pipelined issue, per-lane divergent retry. Tag+data in one dword ->
//    single-copy atomic, no fences needed.
//  - after poll: pack 8 fp16 -> 4 h2-uints, ONE ds_write_b128 into this wave's
//    PRIVATE stage buffer (in-order DS pipe, same-wave write->read, no barrier),
//    then 32 broadcast ds_read_b128 (2 distinct addrs/op = conflict-free) feed
//    128 v_dot2_f32_f16 into 4 acc chains.
// Skew safety: a wave can only publish tag t+2 (overwriting parity buffer of
// tag t) after its poll of tag t+1 succeeded for ALL 512 rows, which requires
// every wave to have published t+1, which requires every wave to have consumed
// tag t into registers. 2 parity buffers suffice.

#define BB 64
#define TT 1024
#define HH 512

typedef _Float16 half2_t __attribute__((ext_vector_type(2)));
typedef unsigned uint4v __attribute__((ext_vector_type(4)));

#define AG __HIP_MEMORY_SCOPE_AGENT

__device__ __forceinline__ float dot2f(unsigned h, unsigned w, float acc) {
    return __builtin_amdgcn_fdot2(__builtin_bit_cast(half2_t, h),
                                  __builtin_bit_cast(half2_t, w), acc, false);
}
__device__ __forceinline__ float fast_tanh(float z) {
    float e = __expf(2.0f * z);
    return fmaf(-2.0f, __builtin_amdgcn_rcpf(e + 1.0f), 1.0f);
}
__device__ __forceinline__ unsigned pack_h2(float a, float b) {
    return __builtin_bit_cast(unsigned, __floats2half2_rn(a, b));
}

// one 16B h-chunk (4 h2-uints) against 4 weight uints into one acc chain
#define DC(j, A) { const uint4v u = hp[j];                        \
    A = dot2f(u[0], wh[4*(j)+0], A); A = dot2f(u[1], wh[4*(j)+1], A); \
    A = dot2f(u[2], wh[4*(j)+2], A); A = dot2f(u[3], wh[4*(j)+3], A); }

__launch_bounds__(256, 1)
__global__ void rnn_wave(const float* __restrict__ x,      // [B,T]
                         const float* __restrict__ W_ih,   // [H]
                         const float* __restrict__ W_hh,   // [H,H]
                         const float* __restrict__ b_ih,   // [H]
                         const float* __restrict__ b_hh,   // [H]
                         const float* __restrict__ W_out,  // [H]
                         const float* __restrict__ b_out,  // [1]
                         float* __restrict__ out,          // [64 + B*H]
                         unsigned* __restrict__ hg)        // [2][B][512] dwords
{
    const int b    = blockIdx.x >> 2;   // batch
    const int q    = blockIdx.x & 3;    // j-quarter 0..3
    const int tid  = threadIdx.x;
    const int wv   = tid >> 6;          // wave 0..3
    const int lane = tid & 63;
    const int r    = lane & 31;         // row within wave's 32-row slice
    const int c    = lane >> 5;         // k-half 0..1

    __shared__ float xrow[TT];                       // 4KB
    __shared__ __align__(16) unsigned stg[4][2][256]; // per-wave h2 stage, 8KB

    for (int s = tid; s < TT; s += 256) xrow[s] = x[b * TT + s];

    // ---- weights: row j = q*128 + wv*32 + r, k halves [256c, 256c+256) ----
    const int jrow = q * 128 + wv * 32 + r;
    unsigned wh[128];
    {
        const float4* rp =
            reinterpret_cast<const float4*>(W_hh + (size_t)jrow * HH + c * 256);
#pragma unroll
        for (int d = 0; d < 64; ++d) {
            const float4 f = rp[d];
            wh[2 * d]     = pack_h2(f.x, f.y);
            wh[2 * d + 1] = pack_h2(f.z, f.w);
        }
    }
    const float wih  = W_ih[jrow];
    const float bias = b_ih[jrow] + b_hh[jrow];

    unsigned* const hb = hg + (size_t)b * 512;   // parity stride = BB*512 dwords
    unsigned* const pollp = hb + lane * 8;
    unsigned* const pubp  = hb + jrow;

    __syncthreads();   // xrow visible (the only barrier in the kernel)

#pragma unroll 1
    for (int t = 0; t < TT; ++t) {
        const int par = t & 1;
        float z;
        if (t > 0) {
            // ---- poll rows [8*lane, 8*lane+8) of tag t (divergent retry) ----
            unsigned* pp = pollp + par * (BB * 512);
            const unsigned tg = (unsigned)t;
            unsigned d0, d1, d2, d3, d4, d5, d6, d7;
            for (;;) {
                d0 = __hip_atomic_load(pp + 0, __ATOMIC_RELAXED, AG);
                d1 = __hip_atomic_load(pp + 1, __ATOMIC_RELAXED, AG);
                d2 = __hip_atomic_load(pp + 2, __ATOMIC_RELAXED, AG);
                d3 = __hip_atomic_load(pp + 3, __ATOMIC_RELAXED, AG);
                d4 = __hip_atomic_load(pp + 4, __ATOMIC_RELAXED, AG);
                d5 = __hip_atomic_load(pp + 5, __ATOMIC_RELAXED, AG);
                d6 = __hip_atomic_load(pp + 6, __ATOMIC_RELAXED, AG);
                d7 = __hip_atomic_load(pp + 7, __ATOMIC_RELAXED, AG);
                const bool ok = ((d0 >> 16) == tg) & ((d1 >> 16) == tg) &
                                ((d2 >> 16) == tg) & ((d3 >> 16) == tg) &
                                ((d4 >> 16) == tg) & ((d5 >> 16) == tg) &
                                ((d6 >> 16) == tg) & ((d7 >> 16) == tg);
                if (ok) break;
            }
            // ---- pack to h2 and stage into this wave's private buffer ----
            uint4v U;
            U[0] = (d0 & 0xFFFFu) | (d1 << 16);
            U[1] = (d2 & 0xFFFFu) | (d3 << 16);
            U[2] = (d4 & 0xFFFFu) | (d5 << 16);
            U[3] = (d6 & 0xFFFFu) | (d7 << 16);
            *(reinterpret_cast<uint4v*>(&stg[wv][par][0]) + lane) = U;
            asm volatile("s_waitcnt lgkmcnt(0)" ::: "memory");
            __builtin_amdgcn_sched_barrier(0);

            // ---- 128 dot2 over this lane's k-half (32 broadcast b128 reads) --
            const uint4v* hp =
                reinterpret_cast<const uint4v*>(&stg[wv][par][0]) + c * 32;
            float a0 = 0.f, a1 = 0.f, a2 = 0.f, a3 = 0.f;
            DC(0, a0)  DC(1, a1)  DC(2, a2)  DC(3, a3)
            DC(4, a0)  DC(5, a1)  DC(6, a2)  DC(7, a3)
            DC(8, a0)  DC(9, a1)  DC(10, a2) DC(11, a3)
            DC(12, a0) DC(13, a1) DC(14, a2) DC(15, a3)
            DC(16, a0) DC(17, a1) DC(18, a2) DC(19, a3)
            DC(20, a0) DC(21, a1) DC(22, a2) DC(23, a3)
            DC(24, a0) DC(25, a1) DC(26, a2) DC(27, a3)
            DC(28, a0) DC(29, a1) DC(30, a2) DC(31, a3)
            z = (a0 + a1) + (a2 + a3);
            z += __shfl_xor(z, 32, 64);   // combine the two k-halves
        } else {
            z = 0.f;
        }
        // ---- lanes 0..31: tanh + publish row jrow with tag t+1 ----
        if (lane < 32) {
            const float zf = fmaf(xrow[t], wih, z + bias);
            const float h  = fast_tanh(zf);
            const unsigned hbits = (unsigned)
                __builtin_bit_cast(unsigned short, (_Float16)h);
            const unsigned val = ((unsigned)(t + 1) << 16) | hbits;
            __hip_atomic_store(pubp + ((t + 1) & 1) * (BB * 512), val,
                               __ATOMIC_RELAXED, AG);
            if (t == TT - 1) out[64 + b * HH + jrow] = h;
        }
    }

    // ---- epilogue: WG q==0, wave 0 computes out[b] = h_last . W_out + b_out --
    if (q == 0 && wv == 0) {
        unsigned* pp = pollp + (TT & 1) * (BB * 512);
        const unsigned tg = (unsigned)TT;
        unsigned d0, d1, d2, d3, d4, d5, d6, d7;
        for (;;) {
            d0 = __hip_atomic_load(pp + 0, __ATOMIC_RELAXED, AG);
            d1 = __hip_atomic_load(pp + 1, __ATOMIC_RELAXED, AG);
            d2 = __hip_atomic_load(pp + 2, __ATOMIC_RELAXED, AG);
            d3 = __hip_atomic_load(pp + 3, __ATOMIC_RELAXED, AG);
            d4 = __hip_atomic_load(pp + 4, __ATOMIC_RELAXED, AG);
            d5 = __hip_atomic_load(pp + 5, __ATOMIC_RELAXED, AG);
            d6 = __hip_atomic_load(pp + 6, __ATOMIC_RELAXED, AG);
            d7 = __hip_atomic_load(pp + 7, __ATOMIC_RELAXED, AG);
            const bool ok = ((d0 >> 16) == tg) & ((d1 >> 16) == tg) &
                            ((d2 >> 16) == tg) & ((d3 >> 16) == tg) &
                            ((d4 >> 16) == tg) & ((d5 >> 16) == tg) &
                            ((d6 >> 16) == tg) & ((d7 >> 16) == tg);
            if (ok) break;
        }
        float s = 0.f;
        const float* wo = W_out + lane * 8;
        s = fmaf(__half2float(__builtin_bit_cast(__half, (unsigned short)(d0 & 0xFFFF))), wo[0], s);
        s = fmaf(__half2float(__builtin_bit_cast(__half, (unsigned short)(d1 & 0xFFFF))), wo[1], s);
        s = fmaf(__half2float(__builtin_bit_cast(__half, (unsigned short)(d2 & 0xFFFF))), wo[2], s);
        s = fmaf(__half2float(__builtin_bit_cast(__half, (unsigned short)(d3 & 0xFFFF))), wo[3], s);
        s = fmaf(__half2float(__builtin_bit_cast(__half, (unsigned short)(d4 & 0xFFFF))), wo[4], s);
        s = fmaf(__half2float(__builtin_bit_cast(__half, (unsigned short)(d5 & 0xFFFF))), wo[5], s);
        s = fmaf(__half2float(__builtin_bit_cast(__half, (unsigned short)(d6 & 0xFFFF))), wo[6], s);
        s = fmaf(__half2float(__builtin_bit_cast(__half, (unsigned short)(d7 & 0xFFFF))), wo[7], s);
#pragma unroll
        for (int off = 32; off; off >>= 1) s += __shfl_down(s, off, 64);
        if (lane == 0) out[b] = s + b_out[0];
    }
}

extern "C" void kernel_launch(void* const* d_in, const int* in_sizes, int n_in,
                              void* d_out, int out_size, void* d_ws, size_t ws_size,
                              hipStream_t stream) {
    const float* x     = (const float*)d_in[0];  // inputs [B,T,1]
    // d_in[1] = state (ignored; reference uses zero initial hidden state)
    const float* W_ih  = (const float*)d_in[2];
    const float* W_hh  = (const float*)d_in[3];
    const float* b_ih  = (const float*)d_in[4];
    const float* b_hh  = (const float*)d_in[5];
    const float* W_out = (const float*)d_in[6];
    const float* b_out = (const float*)d_in[7];

    unsigned* hg = (unsigned*)d_ws;   // [2][64][512] dwords = 256KB

    // tags must start != any step tag (memset 0; ws not re-poisoned per replay)
    hipMemsetAsync(hg, 0, 2ull * BB * 512 * sizeof(unsigned), stream);

    rnn_wave<<<dim3(BB * 4), dim3(256), 0, stream>>>(
        x, W_ih, W_hh, b_ih, b_hh, W_out, b_out, (float*)d_out, hg);
}

// Round 10
// 1116.034 us; speedup vs baseline: 3.1956x; 3.1956x over previous
//
#include <hip/hip_runtime.h>
#include <hip/hip_fp16.h>

// RNN h_{t+1} = tanh(x_t*W_ih + b_ih + b_hh + h_t @ W_hh^T), T=1024, B=64, H=512.
//
// Round 10: PARTIAL-SUM exchange, zero barriers in the loop.
// 256 WGs = 64 batches x 4 k-slices; 256 thr (4 waves).
//  - WG (b,q) owns k-slice [128q,128q+128) for ALL 512 j-rows. Thread (wv,lane)
//    owns adjacent rows j0=128wv+2lane, j1=j0+1: two 64-uint fp16 weight arrays
//    (R2-proven arch-VGPR shape, VGPR=136 measured there).
//  - Per step each thread publishes ONE 8B word {tag:32|fp16 pA|fp16 pB} =
//    its rows' partial dot over the WG's k-slice. Straight from accumulators:
//    no barrier, no parts LDS, no publisher-side reduce on the serial path.
//  - Consumer side: lane needs h-rows c0=128q+2lane, c1=c0+1 (the WG's k-slice
//    values for next step) = pair (64q+lane) from each of the 4 WGs: 4 x 8B
//    polls, sum 4 partials, add xp, tanh -> 2 fp16 -> 1 dword -> private wave
//    stage (same-wave DS ordering, no barrier) -> 16 broadcast ds_read_b128
//    feed 128 v_dot2_f32_f16.
// Tags strictly increase within a run; hipMemsetAsync zeroes tags per call, so
// no cross-replay aliasing. Parity double-buffer; publishing tag s+1 requires
// having consumed tag s, which requires all WGs published s, which required
// all consumed s-1 -> overwrite-safe with 2 parities.

#define BB 64
#define TT 1024
#define HH 512
#define AG __HIP_MEMORY_SCOPE_AGENT

typedef _Float16 half2_t __attribute__((ext_vector_type(2)));
typedef unsigned uint4v __attribute__((ext_vector_type(4)));

__device__ __forceinline__ float dot2f(unsigned h, unsigned w, float acc) {
    return __builtin_amdgcn_fdot2(__builtin_bit_cast(half2_t, h),
                                  __builtin_bit_cast(half2_t, w), acc, false);
}
__device__ __forceinline__ float fast_tanh(float z) {
    float e = __expf(2.0f * z);
    return fmaf(-2.0f, __builtin_amdgcn_rcpf(e + 1.0f), 1.0f);
}
__device__ __forceinline__ unsigned pack_h2(float a, float b) {
    return __builtin_bit_cast(unsigned, __floats2half2_rn(a, b));
}
__device__ __forceinline__ float lo_f(unsigned long long v) {
    return __low2float(__builtin_bit_cast(__half2, (unsigned)v));
}
__device__ __forceinline__ float hi_f(unsigned long long v) {
    return __high2float(__builtin_bit_cast(__half2, (unsigned)v));
}

__launch_bounds__(256, 1)
__global__ void rnn_part(const float* __restrict__ x,      // [B,T]
                         const float* __restrict__ W_ih,   // [H]
                         const float* __restrict__ W_hh,   // [H,H]
                         const float* __restrict__ b_ih,   // [H]
                         const float* __restrict__ b_hh,   // [H]
                         const float* __restrict__ W_out,  // [H]
                         const float* __restrict__ b_out,  // [1]
                         float* __restrict__ out,          // [64 + B*H]
                         unsigned long long* __restrict__ pg) // [2][B][4][256]
{
    const int b    = blockIdx.x >> 2;   // batch
    const int q    = blockIdx.x & 3;    // k-slice of this WG
    const int tid  = threadIdx.x;
    const int wv   = tid >> 6;
    const int lane = tid & 63;

    __shared__ float xrow[TT];                 // 4KB
    __shared__ unsigned stage[4][2][64];       // per-wave h2 stage, 2KB

    for (int s = tid; s < TT; s += 256) xrow[s] = x[b * TT + s];

    // ---- publisher rows j0,j1 over k in [128q, 128q+128): 128 uints in VGPRs
    const int j0 = 128 * wv + 2 * lane;
    const int j1 = j0 + 1;
    unsigned wh0[64], wh1[64];
    {
        const float4* r0 = reinterpret_cast<const float4*>(W_hh + (size_t)j0 * HH + 128 * q);
        const float4* r1 = reinterpret_cast<const float4*>(W_hh + (size_t)j1 * HH + 128 * q);
#pragma unroll
        for (int d = 0; d < 32; ++d) {
            const float4 a = r0[d], c = r1[d];
            wh0[2 * d]     = pack_h2(a.x, a.y);
            wh0[2 * d + 1] = pack_h2(a.z, a.w);
            wh1[2 * d]     = pack_h2(c.x, c.y);
            wh1[2 * d + 1] = pack_h2(c.z, c.w);
        }
    }

    // ---- consumer rows c0,c1 = this WG's k-slice values (pair 64q+lane)
    const int c0 = 128 * q + 2 * lane;
    const int c1 = c0 + 1;
    const float wihA = W_ih[c0], wihB = W_ih[c1];
    const float bA = b_ih[c0] + b_hh[c0];
    const float bB = b_ih[c1] + b_hh[c1];

    const size_t PSTRIDE = (size_t)BB * 4 * 256;     // u64s per parity
    unsigned long long* const base = pg + (size_t)b * 4 * 256;
    unsigned long long* const cp   = base + 64 * q + lane;   // + wg*256 (+par)
    unsigned long long* const pub  = base + (size_t)q * 256 + 64 * wv + lane;

    __syncthreads();   // xrow visible — the only barrier in the kernel

#pragma unroll 1
    for (int s = 1; s <= TT; ++s) {
        const int par = s & 1;
        const size_t po = (size_t)par * PSTRIDE;
        float zA, zB;
        if (s > 1) {
            // ---- poll the 4 partials of rows c0,c1 (tag s) ----
            unsigned long long v0, v1, v2, v3;
            const unsigned tg = (unsigned)s;
            for (;;) {
                v0 = __hip_atomic_load(cp + po + 0 * 256, __ATOMIC_RELAXED, AG);
                v1 = __hip_atomic_load(cp + po + 1 * 256, __ATOMIC_RELAXED, AG);
                v2 = __hip_atomic_load(cp + po + 2 * 256, __ATOMIC_RELAXED, AG);
                v3 = __hip_atomic_load(cp + po + 3 * 256, __ATOMIC_RELAXED, AG);
                const bool ok = ((unsigned)(v0 >> 32) == tg) &
                                ((unsigned)(v1 >> 32) == tg) &
                                ((unsigned)(v2 >> 32) == tg) &
                                ((unsigned)(v3 >> 32) == tg);
                if (ok) break;
            }
            zA = (lo_f(v0) + lo_f(v1)) + (lo_f(v2) + lo_f(v3));
            zB = (hi_f(v0) + hi_f(v1)) + (hi_f(v2) + hi_f(v3));
        } else {
            zA = 0.f; zB = 0.f;   // h_0 = 0
        }
        const float xt = xrow[s - 1];
        const float hA = fast_tanh(fmaf(xt, wihA, zA + bA));
        const float hB = fast_tanh(fmaf(xt, wihB, zB + bB));
        stage[wv][par][lane] = pack_h2(hA, hB);      // same-wave DS, in-order

        if (s == TT) {
            if (wv == 0) {                            // final state out
                out[64 + b * HH + c0] = hA;
                out[64 + b * HH + c1] = hB;
            }
        } else {
            // ---- 128 dot2 over this WG's k-slice; publish partials tag s+1 --
            const uint4v* hp = reinterpret_cast<const uint4v*>(&stage[wv][par][0]);
            float a0 = 0.f, a1 = 0.f, a2 = 0.f, a3 = 0.f;
#pragma unroll
            for (int c = 0; c < 8; ++c) {
                const uint4v u = hp[c];
                a0 = dot2f(u[0], wh0[4*c+0], a0); a1 = dot2f(u[0], wh1[4*c+0], a1);
                a0 = dot2f(u[1], wh0[4*c+1], a0); a1 = dot2f(u[1], wh1[4*c+1], a1);
                a0 = dot2f(u[2], wh0[4*c+2], a0); a1 = dot2f(u[2], wh1[4*c+2], a1);
                a0 = dot2f(u[3], wh0[4*c+3], a0); a1 = dot2f(u[3], wh1[4*c+3], a1);
            }
#pragma unroll
            for (int c = 8; c < 16; ++c) {
                const uint4v u = hp[c];
                a2 = dot2f(u[0], wh0[4*c+0], a2); a3 = dot2f(u[0], wh1[4*c+0], a3);
                a2 = dot2f(u[1], wh0[4*c+1], a2); a3 = dot2f(u[1], wh1[4*c+1], a3);
                a2 = dot2f(u[2], wh0[4*c+2], a2); a3 = dot2f(u[2], wh1[4*c+2], a3);
                a2 = dot2f(u[3], wh0[4*c+3], a2); a3 = dot2f(u[3], wh1[4*c+3], a3);
            }
            const float pA = a0 + a2, pB = a1 + a3;
            const unsigned long long val =
                ((unsigned long long)(unsigned)(s + 1) << 32) | pack_h2(pA, pB);
            __hip_atomic_store(pub + (size_t)((s + 1) & 1) * PSTRIDE, val,
                               __ATOMIC_RELAXED, AG);
        }
    }

    // ---- epilogue: WG q==0 wave 0 rebuilds h_T from tag-TT partials ----
    if (q == 0 && wv == 0) {
        const size_t po = (size_t)(TT & 1) * PSTRIDE;
        float sacc = 0.f;
        const float xt = xrow[TT - 1];
#pragma unroll
        for (int pp = 0; pp < 4; ++pp) {
            const int P = 64 * pp + lane;     // pair -> rows 2P, 2P+1
            unsigned long long v0, v1, v2, v3;
            const unsigned tg = (unsigned)TT;
            for (;;) {
                v0 = __hip_atomic_load(base + po + 0 * 256 + P, __ATOMIC_RELAXED, AG);
                v1 = __hip_atomic_load(base + po + 1 * 256 + P, __ATOMIC_RELAXED, AG);
                v2 = __hip_atomic_load(base + po + 2 * 256 + P, __ATOMIC_RELAXED, AG);
                v3 = __hip_atomic_load(base + po + 3 * 256 + P, __ATOMIC_RELAXED, AG);
                const bool ok = ((unsigned)(v0 >> 32) == tg) &
                                ((unsigned)(v1 >> 32) == tg) &
                                ((unsigned)(v2 >> 32) == tg) &
                                ((unsigned)(v3 >> 32) == tg);
                if (ok) break;
            }
            const int rA = 2 * P, rB = rA + 1;
            const float zA = (lo_f(v0) + lo_f(v1)) + (lo_f(v2) + lo_f(v3));
            const float zB = (hi_f(v0) + hi_f(v1)) + (hi_f(v2) + hi_f(v3));
            const float hA = fast_tanh(fmaf(xt, W_ih[rA], zA + b_ih[rA] + b_hh[rA]));
            const float hB = fast_tanh(fmaf(xt, W_ih[rB], zB + b_ih[rB] + b_hh[rB]));
            sacc = fmaf(hA, W_out[rA], sacc);
            sacc = fmaf(hB, W_out[rB], sacc);
        }
#pragma unroll
        for (int off = 32; off; off >>= 1) sacc += __shfl_down(sacc, off, 64);
        if (lane == 0) out[b] = sacc + b_out[0];
    }
}

extern "C" void kernel_launch(void* const* d_in, const int* in_sizes, int n_in,
                              void* d_out, int out_size, void* d_ws, size_t ws_size,
                              hipStream_t stream) {
    const float* x     = (const float*)d_in[0];  // inputs [B,T,1]
    // d_in[1] = state (ignored; reference uses zero initial hidden state)
    const float* W_ih  = (const float*)d_in[2];
    const float* W_hh  = (const float*)d_in[3];
    const float* b_ih  = (const float*)d_in[4];
    const float* b_hh  = (const float*)d_in[5];
    const float* W_out = (const float*)d_in[6];
    const float* b_out = (const float*)d_in[7];

    unsigned long long* pg = (unsigned long long*)d_ws;  // [2][64][4][256] = 1MB

    // zero tags every call (ws is not re-poisoned between timed replays)
    hipMemsetAsync(pg, 0, 2ull * BB * 4 * 256 * 8, stream);

    rnn_part<<<dim3(BB * 4), dim3(256), 0, stream>>>(
        x, W_ih, W_hh, b_ih, b_hh, W_out, b_out, (float*)d_out, pg);
}